// Round 8
// baseline (412.008 us; speedup 1.0000x reference)
//
#include <hip/hip_runtime.h>
#include <hip/hip_bf16.h>
#include <math.h>
#include <stdint.h>

#define BATCH 8
#define SEQ   1024
#define DIM   768
#define HEADS 12
#define DHEAD 64
#define TOK   (BATCH*SEQ)      // 8192 rows
#define INNER 768
#define FFDIM 3072
#define QKVN  2304
#define QKLD  1536             // qk buffer row stride (Q,K only; V split out)

typedef float floatx4 __attribute__((ext_vector_type(4)));
typedef __bf16 bf16x8 __attribute__((ext_vector_type(8)));

__device__ __forceinline__ float b2f(uint16_t u) {
    return __uint_as_float(((uint32_t)u) << 16);
}
__device__ __forceinline__ uint16_t f2b(float f) {
    uint32_t x = __float_as_uint(f);
    x += 0x7fffu + ((x >> 16) & 1u);   // RNE
    return (uint16_t)(x >> 16);
}
// pack 2 f32 -> 2 bf16 (RNE) in one instruction; no builtin on gfx950
__device__ __forceinline__ uint32_t cvt_pk_bf16(float lo, float hi) {
    uint32_t r;
    asm("v_cvt_pk_bf16_f32 %0, %1, %2" : "=v"(r) : "v"(lo), "v"(hi));
    return r;
}
// raw transcendental ops (1 inst each, per cdna4_isa §3)
__device__ __forceinline__ float exp2_fast(float x) {
    float r; asm("v_exp_f32 %0, %1" : "=v"(r) : "v"(x)); return r;
}
__device__ __forceinline__ float rcp_fast(float x) {
    float r; asm("v_rcp_f32 %0, %1" : "=v"(r) : "v"(x)); return r;
}

// exact-GELU via A&S 7.1.26 erf approx (|erf err| <= 1.5e-7, way below bf16 eps)
__device__ __forceinline__ float gelu_exact(float v) {
    float x  = v * 0.70710678f;
    float ax = fabsf(x);
    float t  = rcp_fast(fmaf(0.3275911f, ax, 1.0f));
    float poly = t * fmaf(t, fmaf(t, fmaf(t, fmaf(t, 1.061405429f, -1.453152027f),
                          1.421413741f), -0.284496736f), 0.254829592f);
    float e = 1.0f - poly * exp2_fast(x * x * -1.44269504f);
    float erfv = copysignf(e, x);
    return 0.5f * v * (1.0f + erfv);
}

// async global->LDS, 16B per lane (m97 pattern; LDS dest = base + lane*16)
__device__ __forceinline__ void gload_lds16(const uint16_t* g, uint16_t* l) {
    __builtin_amdgcn_global_load_lds(
        (const __attribute__((address_space(1))) uint32_t*)g,
        (__attribute__((address_space(3))) uint32_t*)l, 16, 0, 0);
}

// ---- fused fp32->bf16 convert + transpose for ALL four weights, one launch ----
// tiles: qkv 72x24=1728 | out 24x24=576 | ff1 96x24=2304 | ff2 24x96=2304 -> 6912
__global__ __launch_bounds__(256) void transpose_all(
    const float* __restrict__ w_qkv, const float* __restrict__ w_out,
    const float* __restrict__ w_ff1, const float* __restrict__ w_ff2,
    uint16_t* __restrict__ WqT, uint16_t* __restrict__ WoT,
    uint16_t* __restrict__ W1T, uint16_t* __restrict__ W2T)
{
    __shared__ float tile[32][33];
    int bid = blockIdx.x;
    const float* in; uint16_t* outp; int R, C, tx, ty;
    if (bid < 1728)      { in = w_qkv; outp = WqT; R = 768;  C = 2304; tx = bid % 72;            ty = bid / 72; }
    else if (bid < 2304) { int q = bid - 1728; in = w_out; outp = WoT; R = 768;  C = 768;  tx = q % 24; ty = q / 24; }
    else if (bid < 4608) { int q = bid - 2304; in = w_ff1; outp = W1T; R = 768;  C = 3072; tx = q % 96; ty = q / 96; }
    else                 { int q = bid - 4608; in = w_ff2; outp = W2T; R = 3072; C = 768;  tx = q % 24; ty = q / 24; }
    int c0 = tx * 32, r0 = ty * 32;
    int x = threadIdx.x;   // 0..31
    int y = threadIdx.y;   // 0..7
    #pragma unroll
    for (int i = y; i < 32; i += 8)
        tile[i][x] = in[(size_t)(r0 + i) * C + c0 + x];
    __syncthreads();
    #pragma unroll
    for (int i = y; i < 32; i += 8)
        outp[(size_t)(c0 + i) * R + r0 + x] = f2b(tile[x][i]);
}

// ---- LayerNorm: 4 waves/block, one wave per row of 768, fp32 in, bf16 out ----
__global__ __launch_bounds__(256) void ln_naive(
    const float* __restrict__ x, const float* __restrict__ g,
    const float* __restrict__ be, uint16_t* __restrict__ y)
{
    const int lane = threadIdx.x & 63;
    const size_t row = blockIdx.x * 4 + (threadIdx.x >> 6);
    float v[12];
    float s = 0.f, ss = 0.f;
    #pragma unroll
    for (int j = 0; j < 12; j++) {
        int idx = lane + j * 64;
        float f = x[row * DIM + idx];
        v[j] = f; s += f; ss += f * f;
    }
    #pragma unroll
    for (int off = 32; off > 0; off >>= 1) {
        s  += __shfl_xor(s, off);
        ss += __shfl_xor(ss, off);
    }
    const float mu = s * (1.f / DIM);
    const float var = ss * (1.f / DIM) - mu * mu;
    const float rstd = rsqrtf(var + 1e-5f);
    #pragma unroll
    for (int j = 0; j < 12; j++) {
        int idx = lane + j * 64;
        y[row * DIM + idx] = f2b((v[j] - mu) * rstd * g[idx] + be[idx]);
    }
}

// ---- MFMA GEMM, depth-2 pipeline, counted vmcnt (T4), triple-buffer LDS ----
// C[M][N] = A[M][K](lda) @ Bt[N][K](ldbt)^T, 128x128 tile, BK=32.
// ROUND-6 KNOWN-GOOD FORM (57.4us QKV, VGPR 72). Round-7's unroll-3 +
// ds_read-first variant regressed to 70.9us @ VGPR 116 — reverted.
// Wait ledger: prologue stages tiles 0,1 (8 loads/wave). Iter t: vmcnt(4)
// [tile t landed; t+1 in flight] -> s_barrier [landed for ALL waves] ->
// stage tile t+2 into buf (t+2)%3 [readers finished at t-1, proven by this
// barrier] -> compute buf t%3. Last iter waits vmcnt(0).
// VSPLIT: tiles with tileN>=1536 write transposed to vt[b][d][s] (QKV launch).
#define GEMM_STAGE(buf, kk) do {                                                            \
    _Pragma("unroll")                                                                       \
    for (int i = 0; i < 2; i++) {                                                           \
        int row = i * 64 + srow;                                                            \
        gload_lds16(A  + (size_t)(tileM + row) * lda  + (kk) + scol, &a_s[buf][row * 32 + scol]); \
        gload_lds16(Bt + (size_t)(tileN + row) * ldbt + (kk) + scol, &b_s[buf][row * 32 + scol]); \
    } } while (0)

template<bool BIAS, bool GELU, bool RES, bool OUTF, bool VSPLIT>
__global__ __launch_bounds__(256) void gemm_bt(
    const uint16_t* __restrict__ A, const uint16_t* __restrict__ Bt,
    void* C, const float* __restrict__ bias, int bias_off,
    const float* res, int N, int K, int lda, int ldbt, int ldc,
    uint16_t* __restrict__ vt)
{
    __shared__ __align__(16) uint16_t a_s[3][128 * 32];
    __shared__ __align__(16) uint16_t b_s[3][128 * 32];
    const int tid = threadIdx.x;
    const int wave = tid >> 6, lane = tid & 63;
    const int wr = wave >> 1, wc = wave & 1;

    // T1: bijective XCD-chunked swizzle (all launches have nwg % 8 == 0).
    const int nwg = gridDim.x * gridDim.y;
    int bid = blockIdx.y * gridDim.x + blockIdx.x;
    if ((nwg & 7) == 0)
        bid = (bid & 7) * (nwg >> 3) + (bid >> 3);
    const int tileM = (bid / gridDim.x) * 128;
    const int tileN = (bid % gridDim.x) * 128;

    floatx4 acc[4][4] = {};

    const int scol = (tid & 3) * 8;      // byte off = tid*16 (DMA-compatible)
    const int srow = tid >> 2;           // 0..63
    const int lm = lane & 15;
    const int lq = lane >> 4;
    const int kq = lq * 8;

    const int nt = K >> 5;               // >= 24 for all launches

    // prologue: stage tiles 0 and 1 (8 outstanding loads per wave)
    GEMM_STAGE(0, 0);
    GEMM_STAGE(1, 32);

    int rd = 0, st = 2;
    for (int t = 0; t < nt; ++t) {
        // counted wait: tile t's 4 loads done, tile t+1's may still fly
        if (t == nt - 1) asm volatile("s_waitcnt vmcnt(0)" ::: "memory");
        else             asm volatile("s_waitcnt vmcnt(4)" ::: "memory");
        __builtin_amdgcn_s_barrier();
        __builtin_amdgcn_sched_barrier(0);   // pin ds_reads below the barrier

        if (t + 2 < nt) GEMM_STAGE(st, (t + 2) * 32);

        bf16x8 af[4], bfr[4];
        #pragma unroll
        for (int rt = 0; rt < 4; rt++) {
            int r = wr * 64 + rt * 16 + lm;
            af[rt] = *(const bf16x8*)&a_s[rd][r * 32 + kq];
        }
        #pragma unroll
        for (int ntt = 0; ntt < 4; ntt++) {
            int n = wc * 64 + ntt * 16 + lm;
            bfr[ntt] = *(const bf16x8*)&b_s[rd][n * 32 + kq];
        }
        #pragma unroll
        for (int rt = 0; rt < 4; rt++)
            #pragma unroll
            for (int ntt = 0; ntt < 4; ntt++)
                acc[rt][ntt] = __builtin_amdgcn_mfma_f32_16x16x32_bf16(
                    af[rt], bfr[ntt], acc[rt][ntt], 0, 0, 0);

        rd = rd + 1; if (rd == 3) rd = 0;
        st = st + 1; if (st == 3) st = 0;
    }

    // epilogue: C/D layout col=lane&15, row=(lane>>4)*4+reg (m89/m91 verified)
    const bool vpath = VSPLIT && (tileN >= 1536);
    #pragma unroll
    for (int rt = 0; rt < 4; rt++) {
        int r0 = tileM + wr * 64 + rt * 16 + lq * 4;
        #pragma unroll
        for (int ntt = 0; ntt < 4; ntt++) {
            int cg = tileN + wc * 64 + ntt * 16 + lm;
            if (vpath) {
                // V columns -> vT[b][d][s], 4 consecutive s packed into 8B
                int d = cg - 1536;
                int bb = r0 >> 10, s0 = r0 & 1023;
                uint32_t p0 = (uint32_t)f2b(acc[rt][ntt][0]) | ((uint32_t)f2b(acc[rt][ntt][1]) << 16);
                uint32_t p1 = (uint32_t)f2b(acc[rt][ntt][2]) | ((uint32_t)f2b(acc[rt][ntt][3]) << 16);
                uint2 pk; pk.x = p0; pk.y = p1;
                *(uint2*)&vt[((size_t)bb * 768 + d) * 1024 + s0] = pk;
            } else {
                float bvv = BIAS ? bias[bias_off + cg] : 0.f;
                #pragma unroll
                for (int r = 0; r < 4; r++) {
                    float v = acc[rt][ntt][r] + bvv;
                    if (GELU) v = gelu_exact(v);
                    size_t ci = (size_t)(r0 + r) * ldc + cg;
                    if (RES) v += res[ci];
                    if (OUTF) ((float*)C)[ci] = v;
                    else      ((uint16_t*)C)[ci] = f2b(v);
                }
            }
        }
    }
}

// ---- MFMA flash attention v4: 8 waves / QBLK=128, exp2 softmax, defer-max ----
// qk[TOK][1536] (Q,K) + vT[b][768][1024]; grid (8,12,8) remapped so each XCD
// owns one batch b. 512 thr = 8 waves; wave wq owns q-rows [wq*16,+16) of the
// block's 128; KT=64, K/V double-buffered. O written in-place into Q slots.
// LDS [row][128B] with XOR swizzle byte ^= (row&7)<<4 (bits 4-6 only; 8/16B
// blocks stay contiguous; conflict-free for the b128/b64 patterns here).
#define KSWZ(row, cb) ((cb) ^ (((row) & 7) << 4))
#define NKT (SEQ / 64)
#define SM_C   0.18033688f    // 0.125 * log2(e): softmax in exp2 domain
#define SM_THR 11.5416f       // defer-max threshold = 8 nats (T13, HK value)

__global__ __launch_bounds__(512) void flash_mfma(
    uint16_t* qk, const uint16_t* __restrict__ vt)
{
    __shared__ __align__(16) uint16_t k_s[2][64 * 64];
    __shared__ __align__(16) uint16_t v_s[2][64 * 64];
    __shared__ __align__(16) uint16_t p_s[128 * 64];
    char* k_base = (char*)k_s;
    char* v_base = (char*)v_s;
    char* p_c    = (char*)p_s;

    const int t = threadIdx.x;
    const int wq = t >> 6;               // 0..7
    const int lane = t & 63;
    const int lm = lane & 15;
    const int lq = lane >> 4;            // 0..3

    // XCD-chunked remap of 768 flat block ids: HW round-robins flat%8 over
    // XCDs; give each XCD a contiguous 96-block chunk = one batch b.
    int flat = blockIdx.x + 8 * (blockIdx.y + 12 * blockIdx.z);
    int nw = (flat & 7) * 96 + (flat >> 3);
    const int b   = nw / 96;
    const int rem = nw - b * 96;
    const int h   = rem >> 3;
    const int qb  = rem & 7;             // 0..7, 128 q-rows each

    const size_t rowbase = (size_t)b * SEQ;
    const int hcol = h * DHEAD;

    // Q fragment (B operand, rows = q), loaded once before any in-place write
    bf16x8 qf[2];
    {
        const uint16_t* qp = qk + (rowbase + qb*128 + wq*16 + lm) * QKLD + hcol + lq*8;
        qf[0] = *(const bf16x8*)qp;
        qf[1] = *(const bf16x8*)(qp + 32);
    }

    floatx4 O[4] = {};                   // O^T: lane holds q = wq*16+lm, d = nt*16+lq*4+r
    float m_q = -1e30f, l_q = 0.f;       // softmax state in SM_C-scaled (log2) domain

    const int s_row = t >> 3;            // 0..63
    const int s_cb  = (t & 7) * 16;      // byte col 0..112, one uint4/thread/buf
    const size_t kgbase = (rowbase + s_row) * QKLD + INNER + hcol;
    const size_t vgbase = ((size_t)b * 768 + hcol + s_row) * 1024;

    // prologue: tile 0 -> regs -> buf 0
    uint4 kr0, vr0;
    {
        kr0 = *(const uint4*)((const char*)(qk + kgbase) + s_cb);
        vr0 = *(const uint4*)((const char*)(vt + vgbase) + s_cb);
        *(uint4*)&k_base[s_row*128 + KSWZ(s_row, s_cb)] = kr0;
        *(uint4*)&v_base[s_row*128 + KSWZ(s_row, s_cb)] = vr0;
    }

    int cur = 0;
    for (int kt = 0; kt < NKT; ++kt) {
        // loop-top barrier: buf[cur] writes visible; all waves done with buf[cur^1]
        __syncthreads();

        // issue next tile's global loads; latency hides under QK+softmax+PV
        if (kt + 1 < NKT) {
            kr0 = *(const uint4*)((const char*)(qk + kgbase + (size_t)(kt + 1) * 64 * QKLD) + s_cb);
            vr0 = *(const uint4*)((const char*)(vt + vgbase + (size_t)(kt + 1) * 64) + s_cb);
        }

        const char* k_c = k_base + cur * 8192;
        const char* v_c = v_base + cur * 8192;

        // S^T = K Q^T : A = K rows(kpos), B = Q rows(q)
        // out: lane holds q = lm, kpos = nt*16 + lq*4 + r   (raw scores)
        floatx4 S[4];
        __builtin_amdgcn_s_setprio(1);
        #pragma unroll
        for (int nt = 0; nt < 4; nt++) {
            const int row = nt*16 + lm;
            bf16x8 ak0 = *(const bf16x8*)&k_c[row*128 + KSWZ(row, lq*16)];
            bf16x8 ak1 = *(const bf16x8*)&k_c[row*128 + KSWZ(row, 64 + lq*16)];
            floatx4 a = {};
            a = __builtin_amdgcn_mfma_f32_16x16x32_bf16(ak0, qf[0], a, 0, 0, 0);
            a = __builtin_amdgcn_mfma_f32_16x16x32_bf16(ak1, qf[1], a, 0, 0, 0);
            S[nt] = a;
        }
        __builtin_amdgcn_s_setprio(0);

        // online softmax in exp2 domain: raw max tree, scale once, 2 shuffles
        float m0 = fmaxf(fmaxf(S[0][0], S[0][1]), fmaxf(S[0][2], S[0][3]));
        float m1 = fmaxf(fmaxf(S[1][0], S[1][1]), fmaxf(S[1][2], S[1][3]));
        float m2 = fmaxf(fmaxf(S[2][0], S[2][1]), fmaxf(S[2][2], S[2][3]));
        float m3 = fmaxf(fmaxf(S[3][0], S[3][1]), fmaxf(S[3][2], S[3][3]));
        float mx = fmaxf(fmaxf(m0, m1), fmaxf(m2, m3)) * SM_C;
        mx = fmaxf(mx, __shfl_xor(mx, 16));
        mx = fmaxf(mx, __shfl_xor(mx, 32));

        // T13 defer-max: only rescale when the running max grew by > THR
        float mn = m_q;
        if (!__all(mx <= m_q + SM_THR)) {
            mn = fmaxf(m_q, mx);
            float alpha = exp2_fast(m_q - mn);
            m_q = mn;
            l_q *= alpha;
            #pragma unroll
            for (int nt = 0; nt < 4; nt++) {
                O[nt][0] *= alpha; O[nt][1] *= alpha;
                O[nt][2] *= alpha; O[nt][3] *= alpha;
            }
        }

        // p = 2^(S*c - mn): one FMA + one exp per score
        float p[4][4];
        float sum = 0.f;
        #pragma unroll
        for (int nt = 0; nt < 4; nt++) {
            float p0 = exp2_fast(fmaf(S[nt][0], SM_C, -mn));
            float p1 = exp2_fast(fmaf(S[nt][1], SM_C, -mn));
            float p2 = exp2_fast(fmaf(S[nt][2], SM_C, -mn));
            float p3 = exp2_fast(fmaf(S[nt][3], SM_C, -mn));
            p[nt][0] = p0; p[nt][1] = p1; p[nt][2] = p2; p[nt][3] = p3;
            sum += (p0 + p1) + (p2 + p3);
        }
        sum += __shfl_xor(sum, 16);
        sum += __shfl_xor(sum, 32);
        l_q += sum;

        // P -> LDS, vectorized: row q = wq*16+lm (wave-private stripe)
        const int prow = wq*16 + lm;
        #pragma unroll
        for (int nt = 0; nt < 4; nt++) {
            uint2 w;
            w.x = cvt_pk_bf16(p[nt][0], p[nt][1]);
            w.y = cvt_pk_bf16(p[nt][2], p[nt][3]);
            *(uint2*)&p_c[prow*128 + KSWZ(prow, nt*32 + lq*8)] = w;
        }

        // O^T += V^T P^T : A = V^T rows(d), B = P rows(q)
        __builtin_amdgcn_s_setprio(1);
        #pragma unroll
        for (int ks = 0; ks < 2; ks++) {
            bf16x8 bp = *(const bf16x8*)&p_c[prow*128 + KSWZ(prow, ks*64 + lq*16)];
            #pragma unroll
            for (int nt = 0; nt < 4; nt++) {
                const int vrow = nt*16 + lm;
                bf16x8 av = *(const bf16x8*)&v_c[vrow*128 + KSWZ(vrow, ks*64 + lq*16)];
                O[nt] = __builtin_amdgcn_mfma_f32_16x16x32_bf16(av, bp, O[nt], 0, 0, 0);
            }
        }
        __builtin_amdgcn_s_setprio(0);

        // stage tile kt+1 into buf cur^1 (readers of that buf finished last
        // iter, proven by the loop-top barrier; visibility via next barrier)
        if (kt + 1 < NKT) {
            char* kn = k_base + (cur ^ 1) * 8192;
            char* vn = v_base + (cur ^ 1) * 8192;
            *(uint4*)&kn[s_row*128 + KSWZ(s_row, s_cb)] = kr0;
            *(uint4*)&vn[s_row*128 + KSWZ(s_row, s_cb)] = vr0;
        }
        cur ^= 1;
    }

    // write O^T into this block's Q slots: lane q = wq*16+lm, d = nt*16+lq*4+r
    const float linv = rcp_fast(l_q);
    uint16_t* dst = qk + (rowbase + qb*128 + wq*16 + lm) * QKLD + hcol;
    #pragma unroll
    for (int nt = 0; nt < 4; nt++) {
        uint2 w;
        w.x = cvt_pk_bf16(O[nt][0] * linv, O[nt][1] * linv);
        w.y = cvt_pk_bf16(O[nt][2] * linv, O[nt][3] * linv);
        *(uint2*)&dst[nt*16 + lq*4] = w;
    }
}

extern "C" void kernel_launch(void* const* d_in, const int* in_sizes, int n_in,
                              void* d_out, int out_size, void* d_ws, size_t ws_size,
                              hipStream_t stream) {
    const float* x      = (const float*)d_in[0];   // [8192][768] fp32
    const float* ln1_g  = (const float*)d_in[1];
    const float* ln1_b  = (const float*)d_in[2];
    const float* ln2_g  = (const float*)d_in[3];
    const float* ln2_b  = (const float*)d_in[4];
    const float* w_qkv  = (const float*)d_in[5];   // [768][2304]
    const float* w_out  = (const float*)d_in[6];   // [768][768]
    const float* b_out  = (const float*)d_in[7];
    const float* w_ff1  = (const float*)d_in[8];   // [768][3072]
    const float* b_ff1  = (const float*)d_in[9];
    const float* w_ff2  = (const float*)d_in[10];  // [3072][768]
    const float* b_ff2  = (const float*)d_in[11];
    float* out = (float*)d_out;                    // [8192][768] fp32

    // ws layout (uint16 elements), peak 64.5 MB (proven safe)
    uint16_t* ws  = (uint16_t*)d_ws;
    uint16_t* qk  = ws;                            // [8192][1536] Q,K
    uint16_t* ffc = ws;                            // [8192][1536] (reuses dead qk)
    uint16_t* vT  = ws + (size_t)12582912;         // [8][768][1024]
    uint16_t* h   = ws + (size_t)18874368;         // [8192][768]
    uint16_t* WqT = ws + (size_t)25165824;         // [2304][768]
    uint16_t* WoT = ws + (size_t)26935296;         // [768][768]
    uint16_t* W1T = ws + (size_t)27525120;         // [3072][768]
    uint16_t* W2T = ws + (size_t)29884416;         // [768][3072]

    // all four weight transposes in one launch
    hipLaunchKernelGGL(transpose_all, dim3(6912), dim3(32, 8), 0, stream,
                       w_qkv, w_out, w_ff1, w_ff2, WqT, WoT, W1T, W2T);

    // h = LN1(x)
    hipLaunchKernelGGL(ln_naive, dim3(TOK/4), dim3(256), 0, stream, x, ln1_g, ln1_b, h);
    // qk (+vT split) = h @ w_qkv
    hipLaunchKernelGGL((gemm_bt<false, false, false, false, true>), dim3(QKVN/128, TOK/128), dim3(256), 0, stream,
                       h, WqT, qk, nullptr, 0, nullptr, QKVN, DIM, DIM, DIM, QKLD, vT);
    // attention in-place (O -> Q slots of qk)
    hipLaunchKernelGGL(flash_mfma, dim3(SEQ/128, HEADS, BATCH), dim3(512), 0, stream, qk, vT);
    // d_out(fp32) = x + attnO @ w_out + b_out
    hipLaunchKernelGGL((gemm_bt<true, false, true, true, false>), dim3(DIM/128, TOK/128), dim3(256), 0, stream,
                       qk, WoT, out, b_out, 0, x, DIM, INNER, QKLD, DIM, DIM, nullptr);
    // h = LN2(d_out)
    hipLaunchKernelGGL(ln_naive, dim3(TOK/4), dim3(256), 0, stream, out, ln2_g, ln2_b, h);
    // FFN in two hidden chunks of 1536 (ffc reuses dead qk region)
    for (int c = 0; c < 2; c++) {
        hipLaunchKernelGGL((gemm_bt<true, true, false, false, false>), dim3(1536/128, TOK/128), dim3(256), 0, stream,
                           h, W1T + (size_t)c*1536*DIM, ffc, b_ff1, c*1536, nullptr,
                           1536, DIM, DIM, DIM, 1536, nullptr);
        if (c == 0) {
            hipLaunchKernelGGL((gemm_bt<true, false, true, true, false>), dim3(DIM/128, TOK/128), dim3(256), 0, stream,
                               ffc, W2T + (size_t)c*1536, out, b_ff2, 0, out,
                               DIM, 1536, 1536, FFDIM, DIM, nullptr);
        } else {
            hipLaunchKernelGGL((gemm_bt<false, false, true, true, false>), dim3(DIM/128, TOK/128), dim3(256), 0, stream,
                               ffc, W2T + (size_t)c*1536, out, nullptr, 0, out,
                               DIM, 1536, 1536, FFDIM, DIM, nullptr);
        }
    }
}

// Round 9
// 403.100 us; speedup vs baseline: 1.0221x; 1.0221x over previous
//
#include <hip/hip_runtime.h>
#include <hip/hip_bf16.h>
#include <math.h>
#include <stdint.h>

#define BATCH 8
#define SEQ   1024
#define DIM   768
#define HEADS 12
#define DHEAD 64
#define TOK   (BATCH*SEQ)      // 8192 rows
#define INNER 768
#define FFDIM 3072
#define QKVN  2304
#define QKLD  1536             // qk buffer row stride (Q,K only; V split out)

typedef float floatx4 __attribute__((ext_vector_type(4)));
typedef __bf16 bf16x8 __attribute__((ext_vector_type(8)));

__device__ __forceinline__ float b2f(uint16_t u) {
    return __uint_as_float(((uint32_t)u) << 16);
}
__device__ __forceinline__ uint16_t f2b(float f) {
    uint32_t x = __float_as_uint(f);
    x += 0x7fffu + ((x >> 16) & 1u);   // RNE
    return (uint16_t)(x >> 16);
}
// pack 2 f32 -> 2 bf16 (RNE) in one instruction; no builtin on gfx950
__device__ __forceinline__ uint32_t cvt_pk_bf16(float lo, float hi) {
    uint32_t r;
    asm("v_cvt_pk_bf16_f32 %0, %1, %2" : "=v"(r) : "v"(lo), "v"(hi));
    return r;
}
// raw transcendental ops (1 inst each, per cdna4_isa §3)
__device__ __forceinline__ float exp2_fast(float x) {
    float r; asm("v_exp_f32 %0, %1" : "=v"(r) : "v"(x)); return r;
}
__device__ __forceinline__ float rcp_fast(float x) {
    float r; asm("v_rcp_f32 %0, %1" : "=v"(r) : "v"(x)); return r;
}

// exact-GELU via A&S 7.1.26 erf approx (|erf err| <= 1.5e-7, way below bf16 eps)
__device__ __forceinline__ float gelu_exact(float v) {
    float x  = v * 0.70710678f;
    float ax = fabsf(x);
    float t  = rcp_fast(fmaf(0.3275911f, ax, 1.0f));
    float poly = t * fmaf(t, fmaf(t, fmaf(t, fmaf(t, 1.061405429f, -1.453152027f),
                          1.421413741f), -0.284496736f), 0.254829592f);
    float e = 1.0f - poly * exp2_fast(x * x * -1.44269504f);
    float erfv = copysignf(e, x);
    return 0.5f * v * (1.0f + erfv);
}

// ---- fused fp32->bf16 convert + transpose for ALL four weights, one launch ----
// tiles: qkv 72x24=1728 | out 24x24=576 | ff1 96x24=2304 | ff2 24x96=2304 -> 6912
__global__ __launch_bounds__(256) void transpose_all(
    const float* __restrict__ w_qkv, const float* __restrict__ w_out,
    const float* __restrict__ w_ff1, const float* __restrict__ w_ff2,
    uint16_t* __restrict__ WqT, uint16_t* __restrict__ WoT,
    uint16_t* __restrict__ W1T, uint16_t* __restrict__ W2T)
{
    __shared__ float tile[32][33];
    int bid = blockIdx.x;
    const float* in; uint16_t* outp; int R, C, tx, ty;
    if (bid < 1728)      { in = w_qkv; outp = WqT; R = 768;  C = 2304; tx = bid % 72;            ty = bid / 72; }
    else if (bid < 2304) { int q = bid - 1728; in = w_out; outp = WoT; R = 768;  C = 768;  tx = q % 24; ty = q / 24; }
    else if (bid < 4608) { int q = bid - 2304; in = w_ff1; outp = W1T; R = 768;  C = 3072; tx = q % 96; ty = q / 96; }
    else                 { int q = bid - 4608; in = w_ff2; outp = W2T; R = 3072; C = 768;  tx = q % 24; ty = q / 24; }
    int c0 = tx * 32, r0 = ty * 32;
    int x = threadIdx.x;   // 0..31
    int y = threadIdx.y;   // 0..7
    #pragma unroll
    for (int i = y; i < 32; i += 8)
        tile[i][x] = in[(size_t)(r0 + i) * C + c0 + x];
    __syncthreads();
    #pragma unroll
    for (int i = y; i < 32; i += 8)
        outp[(size_t)(c0 + i) * R + r0 + x] = f2b(tile[x][i]);
}

// ---- LayerNorm: 4 waves/block, one wave per row of 768, fp32 in, bf16 out ----
__global__ __launch_bounds__(256) void ln_naive(
    const float* __restrict__ x, const float* __restrict__ g,
    const float* __restrict__ be, uint16_t* __restrict__ y)
{
    const int lane = threadIdx.x & 63;
    const size_t row = blockIdx.x * 4 + (threadIdx.x >> 6);
    float v[12];
    float s = 0.f, ss = 0.f;
    #pragma unroll
    for (int j = 0; j < 12; j++) {
        int idx = lane + j * 64;
        float f = x[row * DIM + idx];
        v[j] = f; s += f; ss += f * f;
    }
    #pragma unroll
    for (int off = 32; off > 0; off >>= 1) {
        s  += __shfl_xor(s, off);
        ss += __shfl_xor(ss, off);
    }
    const float mu = s * (1.f / DIM);
    const float var = ss * (1.f / DIM) - mu * mu;
    const float rstd = rsqrtf(var + 1e-5f);
    #pragma unroll
    for (int j = 0; j < 12; j++) {
        int idx = lane + j * 64;
        y[row * DIM + idx] = f2b((v[j] - mu) * rstd * g[idx] + be[idx]);
    }
}

// ---- MFMA GEMM v3: reg-staged 2-buffer pipeline (flash-proven protocol) ----
// C[M][N] = A[M][K](lda) @ Bt[N][K](ldbt)^T, 128x128 tile, BK=32.
// Theory (R8): global_load_lds into runtime-indexed LDS bufs made the compiler
// insert conservative vmcnt(0) before the ds_reads (alias ambiguity), freezing
// all prior pipeline variants at ~56us. Reg-staging gives the compiler exact
// register dependences: loads for tile t+1 issue at top of body, their vmcnt
// wait lands naturally at the ds_write AFTER the MFMAs.
// Race ledger (== flash_mfma): iter t reads buf[cur] (written at t-1, visible
// via top barrier), writes buf[cur^1] (its readers finished at t-1, proven by
// the same barrier). One __syncthreads per step.
// VSPLIT: tiles with tileN>=1536 write transposed to vt[b][d][s] (QKV launch).
template<bool BIAS, bool GELU, bool RES, bool OUTF, bool VSPLIT>
__global__ __launch_bounds__(256) void gemm_bt(
    const uint16_t* __restrict__ A, const uint16_t* __restrict__ Bt,
    void* C, const float* __restrict__ bias, int bias_off,
    const float* res, int N, int K, int lda, int ldbt, int ldc,
    uint16_t* __restrict__ vt)
{
    __shared__ __align__(16) uint16_t a_s[2][128 * 32];
    __shared__ __align__(16) uint16_t b_s[2][128 * 32];
    const int tid = threadIdx.x;
    const int wave = tid >> 6, lane = tid & 63;
    const int wr = wave >> 1, wc = wave & 1;

    // T1: bijective XCD-chunked swizzle (all launches have nwg % 8 == 0).
    const int nwg = gridDim.x * gridDim.y;
    int bid = blockIdx.y * gridDim.x + blockIdx.x;
    if ((nwg & 7) == 0)
        bid = (bid & 7) * (nwg >> 3) + (bid >> 3);
    const int tileM = (bid / gridDim.x) * 128;
    const int tileN = (bid % gridDim.x) * 128;

    floatx4 acc[4][4] = {};

    const int scol = (tid & 3) * 8;      // 8 u16 = 16B per load
    const int srow = tid >> 2;           // 0..63
    const int lm = lane & 15;
    const int lq = lane >> 4;
    const int kq = lq * 8;

    const uint16_t* Ab0 = A  + (size_t)(tileM + srow) * lda;
    const uint16_t* Ab1 = A  + (size_t)(tileM + 64 + srow) * lda;
    const uint16_t* Bb0 = Bt + (size_t)(tileN + srow) * ldbt;
    const uint16_t* Bb1 = Bt + (size_t)(tileN + 64 + srow) * ldbt;

    const int nt = K >> 5;

    // prologue: tile 0 -> regs -> buf 0
    uint4 ar0, ar1, br0, br1;
    ar0 = *(const uint4*)(Ab0 + scol);
    ar1 = *(const uint4*)(Ab1 + scol);
    br0 = *(const uint4*)(Bb0 + scol);
    br1 = *(const uint4*)(Bb1 + scol);
    *(uint4*)&a_s[0][srow * 32 + scol]        = ar0;
    *(uint4*)&a_s[0][(64 + srow) * 32 + scol] = ar1;
    *(uint4*)&b_s[0][srow * 32 + scol]        = br0;
    *(uint4*)&b_s[0][(64 + srow) * 32 + scol] = br1;

    int cur = 0;
    for (int t = 0; t < nt; ++t) {
        // top barrier: buf[cur] writes visible; all waves done with buf[cur^1]
        __syncthreads();

        // issue next tile's global loads; latency hides under ds_read + MFMA
        if (t + 1 < nt) {
            const int kk = (t + 1) * 32 + scol;
            ar0 = *(const uint4*)(Ab0 + kk);
            ar1 = *(const uint4*)(Ab1 + kk);
            br0 = *(const uint4*)(Bb0 + kk);
            br1 = *(const uint4*)(Bb1 + kk);
        }

        bf16x8 af[4], bfr[4];
        #pragma unroll
        for (int rt = 0; rt < 4; rt++) {
            int r = wr * 64 + rt * 16 + lm;
            af[rt] = *(const bf16x8*)&a_s[cur][r * 32 + kq];
        }
        #pragma unroll
        for (int ntt = 0; ntt < 4; ntt++) {
            int n = wc * 64 + ntt * 16 + lm;
            bfr[ntt] = *(const bf16x8*)&b_s[cur][n * 32 + kq];
        }
        #pragma unroll
        for (int rt = 0; rt < 4; rt++)
            #pragma unroll
            for (int ntt = 0; ntt < 4; ntt++)
                acc[rt][ntt] = __builtin_amdgcn_mfma_f32_16x16x32_bf16(
                    af[rt], bfr[ntt], acc[rt][ntt], 0, 0, 0);

        // write tile t+1 into the other buffer; compiler's vmcnt wait for the
        // loads lands HERE (after the MFMAs), not before the ds_reads
        if (t + 1 < nt) {
            *(uint4*)&a_s[cur ^ 1][srow * 32 + scol]        = ar0;
            *(uint4*)&a_s[cur ^ 1][(64 + srow) * 32 + scol] = ar1;
            *(uint4*)&b_s[cur ^ 1][srow * 32 + scol]        = br0;
            *(uint4*)&b_s[cur ^ 1][(64 + srow) * 32 + scol] = br1;
        }
        cur ^= 1;
    }

    // epilogue: C/D layout col=lane&15, row=(lane>>4)*4+reg (m89/m91 verified)
    const bool vpath = VSPLIT && (tileN >= 1536);
    #pragma unroll
    for (int rt = 0; rt < 4; rt++) {
        int r0 = tileM + wr * 64 + rt * 16 + lq * 4;
        #pragma unroll
        for (int ntt = 0; ntt < 4; ntt++) {
            int cg = tileN + wc * 64 + ntt * 16 + lm;
            if (vpath) {
                // V columns -> vT[b][d][s], 4 consecutive s packed into 8B
                int d = cg - 1536;
                int bb = r0 >> 10, s0 = r0 & 1023;
                uint32_t p0 = (uint32_t)f2b(acc[rt][ntt][0]) | ((uint32_t)f2b(acc[rt][ntt][1]) << 16);
                uint32_t p1 = (uint32_t)f2b(acc[rt][ntt][2]) | ((uint32_t)f2b(acc[rt][ntt][3]) << 16);
                uint2 pk; pk.x = p0; pk.y = p1;
                *(uint2*)&vt[((size_t)bb * 768 + d) * 1024 + s0] = pk;
            } else {
                float bvv = BIAS ? bias[bias_off + cg] : 0.f;
                #pragma unroll
                for (int r = 0; r < 4; r++) {
                    float v = acc[rt][ntt][r] + bvv;
                    if (GELU) v = gelu_exact(v);
                    size_t ci = (size_t)(r0 + r) * ldc + cg;
                    if (RES) v += res[ci];
                    if (OUTF) ((float*)C)[ci] = v;
                    else      ((uint16_t*)C)[ci] = f2b(v);
                }
            }
        }
    }
}

// ---- MFMA flash attention v4: 8 waves / QBLK=128, exp2 softmax, defer-max ----
// qk[TOK][1536] (Q,K) + vT[b][768][1024]; grid (8,12,8) remapped so each XCD
// owns one batch b. 512 thr = 8 waves; wave wq owns q-rows [wq*16,+16) of the
// block's 128; KT=64, K/V double-buffered. O written in-place into Q slots.
// LDS [row][128B] with XOR swizzle byte ^= (row&7)<<4 (bits 4-6 only; 8/16B
// blocks stay contiguous; conflict-free for the b128/b64 patterns here).
#define KSWZ(row, cb) ((cb) ^ (((row) & 7) << 4))
#define NKT (SEQ / 64)
#define SM_C   0.18033688f    // 0.125 * log2(e): softmax in exp2 domain
#define SM_THR 11.5416f       // defer-max threshold = 8 nats (T13, HK value)

__global__ __launch_bounds__(512) void flash_mfma(
    uint16_t* qk, const uint16_t* __restrict__ vt)
{
    __shared__ __align__(16) uint16_t k_s[2][64 * 64];
    __shared__ __align__(16) uint16_t v_s[2][64 * 64];
    __shared__ __align__(16) uint16_t p_s[128 * 64];
    char* k_base = (char*)k_s;
    char* v_base = (char*)v_s;
    char* p_c    = (char*)p_s;

    const int t = threadIdx.x;
    const int wq = t >> 6;               // 0..7
    const int lane = t & 63;
    const int lm = lane & 15;
    const int lq = lane >> 4;            // 0..3

    // XCD-chunked remap of 768 flat block ids: HW round-robins flat%8 over
    // XCDs; give each XCD a contiguous 96-block chunk = one batch b.
    int flat = blockIdx.x + 8 * (blockIdx.y + 12 * blockIdx.z);
    int nw = (flat & 7) * 96 + (flat >> 3);
    const int b   = nw / 96;
    const int rem = nw - b * 96;
    const int h   = rem >> 3;
    const int qb  = rem & 7;             // 0..7, 128 q-rows each

    const size_t rowbase = (size_t)b * SEQ;
    const int hcol = h * DHEAD;

    // Q fragment (B operand, rows = q), loaded once before any in-place write
    bf16x8 qf[2];
    {
        const uint16_t* qp = qk + (rowbase + qb*128 + wq*16 + lm) * QKLD + hcol + lq*8;
        qf[0] = *(const bf16x8*)qp;
        qf[1] = *(const bf16x8*)(qp + 32);
    }

    floatx4 O[4] = {};                   // O^T: lane holds q = wq*16+lm, d = nt*16+lq*4+r
    float m_q = -1e30f, l_q = 0.f;       // softmax state in SM_C-scaled (log2) domain

    const int s_row = t >> 3;            // 0..63
    const int s_cb  = (t & 7) * 16;      // byte col 0..112, one uint4/thread/buf
    const size_t kgbase = (rowbase + s_row) * QKLD + INNER + hcol;
    const size_t vgbase = ((size_t)b * 768 + hcol + s_row) * 1024;

    // prologue: tile 0 -> regs -> buf 0
    uint4 kr0, vr0;
    {
        kr0 = *(const uint4*)((const char*)(qk + kgbase) + s_cb);
        vr0 = *(const uint4*)((const char*)(vt + vgbase) + s_cb);
        *(uint4*)&k_base[s_row*128 + KSWZ(s_row, s_cb)] = kr0;
        *(uint4*)&v_base[s_row*128 + KSWZ(s_row, s_cb)] = vr0;
    }

    int cur = 0;
    for (int kt = 0; kt < NKT; ++kt) {
        // loop-top barrier: buf[cur] writes visible; all waves done with buf[cur^1]
        __syncthreads();

        // issue next tile's global loads; latency hides under QK+softmax+PV
        if (kt + 1 < NKT) {
            kr0 = *(const uint4*)((const char*)(qk + kgbase + (size_t)(kt + 1) * 64 * QKLD) + s_cb);
            vr0 = *(const uint4*)((const char*)(vt + vgbase + (size_t)(kt + 1) * 64) + s_cb);
        }

        const char* k_c = k_base + cur * 8192;
        const char* v_c = v_base + cur * 8192;

        // S^T = K Q^T : A = K rows(kpos), B = Q rows(q)
        // out: lane holds q = lm, kpos = nt*16 + lq*4 + r   (raw scores)
        floatx4 S[4];
        __builtin_amdgcn_s_setprio(1);
        #pragma unroll
        for (int nt = 0; nt < 4; nt++) {
            const int row = nt*16 + lm;
            bf16x8 ak0 = *(const bf16x8*)&k_c[row*128 + KSWZ(row, lq*16)];
            bf16x8 ak1 = *(const bf16x8*)&k_c[row*128 + KSWZ(row, 64 + lq*16)];
            floatx4 a = {};
            a = __builtin_amdgcn_mfma_f32_16x16x32_bf16(ak0, qf[0], a, 0, 0, 0);
            a = __builtin_amdgcn_mfma_f32_16x16x32_bf16(ak1, qf[1], a, 0, 0, 0);
            S[nt] = a;
        }
        __builtin_amdgcn_s_setprio(0);

        // online softmax in exp2 domain: raw max tree, scale once, 2 shuffles
        float m0 = fmaxf(fmaxf(S[0][0], S[0][1]), fmaxf(S[0][2], S[0][3]));
        float m1 = fmaxf(fmaxf(S[1][0], S[1][1]), fmaxf(S[1][2], S[1][3]));
        float m2 = fmaxf(fmaxf(S[2][0], S[2][1]), fmaxf(S[2][2], S[2][3]));
        float m3 = fmaxf(fmaxf(S[3][0], S[3][1]), fmaxf(S[3][2], S[3][3]));
        float mx = fmaxf(fmaxf(m0, m1), fmaxf(m2, m3)) * SM_C;
        mx = fmaxf(mx, __shfl_xor(mx, 16));
        mx = fmaxf(mx, __shfl_xor(mx, 32));

        // T13 defer-max: only rescale when the running max grew by > THR
        float mn = m_q;
        if (!__all(mx <= m_q + SM_THR)) {
            mn = fmaxf(m_q, mx);
            float alpha = exp2_fast(m_q - mn);
            m_q = mn;
            l_q *= alpha;
            #pragma unroll
            for (int nt = 0; nt < 4; nt++) {
                O[nt][0] *= alpha; O[nt][1] *= alpha;
                O[nt][2] *= alpha; O[nt][3] *= alpha;
            }
        }

        // p = 2^(S*c - mn): one FMA + one exp per score
        float p[4][4];
        float sum = 0.f;
        #pragma unroll
        for (int nt = 0; nt < 4; nt++) {
            float p0 = exp2_fast(fmaf(S[nt][0], SM_C, -mn));
            float p1 = exp2_fast(fmaf(S[nt][1], SM_C, -mn));
            float p2 = exp2_fast(fmaf(S[nt][2], SM_C, -mn));
            float p3 = exp2_fast(fmaf(S[nt][3], SM_C, -mn));
            p[nt][0] = p0; p[nt][1] = p1; p[nt][2] = p2; p[nt][3] = p3;
            sum += (p0 + p1) + (p2 + p3);
        }
        sum += __shfl_xor(sum, 16);
        sum += __shfl_xor(sum, 32);
        l_q += sum;

        // P -> LDS, vectorized: row q = wq*16+lm (wave-private stripe)
        const int prow = wq*16 + lm;
        #pragma unroll
        for (int nt = 0; nt < 4; nt++) {
            uint2 w;
            w.x = cvt_pk_bf16(p[nt][0], p[nt][1]);
            w.y = cvt_pk_bf16(p[nt][2], p[nt][3]);
            *(uint2*)&p_c[prow*128 + KSWZ(prow, nt*32 + lq*8)] = w;
        }

        // O^T += V^T P^T : A = V^T rows(d), B = P rows(q)
        __builtin_amdgcn_s_setprio(1);
        #pragma unroll
        for (int ks = 0; ks < 2; ks++) {
            bf16x8 bp = *(const bf16x8*)&p_c[prow*128 + KSWZ(prow, ks*64 + lq*16)];
            #pragma unroll
            for (int nt = 0; nt < 4; nt++) {
                const int vrow = nt*16 + lm;
                bf16x8 av = *(const bf16x8*)&v_c[vrow*128 + KSWZ(vrow, ks*64 + lq*16)];
                O[nt] = __builtin_amdgcn_mfma_f32_16x16x32_bf16(av, bp, O[nt], 0, 0, 0);
            }
        }
        __builtin_amdgcn_s_setprio(0);

        // stage tile kt+1 into buf cur^1 (readers of that buf finished last
        // iter, proven by the loop-top barrier; visibility via next barrier)
        if (kt + 1 < NKT) {
            char* kn = k_base + (cur ^ 1) * 8192;
            char* vn = v_base + (cur ^ 1) * 8192;
            *(uint4*)&kn[s_row*128 + KSWZ(s_row, s_cb)] = kr0;
            *(uint4*)&vn[s_row*128 + KSWZ(s_row, s_cb)] = vr0;
        }
        cur ^= 1;
    }

    // write O^T into this block's Q slots: lane q = wq*16+lm, d = nt*16+lq*4+r
    const float linv = rcp_fast(l_q);
    uint16_t* dst = qk + (rowbase + qb*128 + wq*16 + lm) * QKLD + hcol;
    #pragma unroll
    for (int nt = 0; nt < 4; nt++) {
        uint2 w;
        w.x = cvt_pk_bf16(O[nt][0] * linv, O[nt][1] * linv);
        w.y = cvt_pk_bf16(O[nt][2] * linv, O[nt][3] * linv);
        *(uint2*)&dst[nt*16 + lq*4] = w;
    }
}

extern "C" void kernel_launch(void* const* d_in, const int* in_sizes, int n_in,
                              void* d_out, int out_size, void* d_ws, size_t ws_size,
                              hipStream_t stream) {
    const float* x      = (const float*)d_in[0];   // [8192][768] fp32
    const float* ln1_g  = (const float*)d_in[1];
    const float* ln1_b  = (const float*)d_in[2];
    const float* ln2_g  = (const float*)d_in[3];
    const float* ln2_b  = (const float*)d_in[4];
    const float* w_qkv  = (const float*)d_in[5];   // [768][2304]
    const float* w_out  = (const float*)d_in[6];   // [768][768]
    const float* b_out  = (const float*)d_in[7];
    const float* w_ff1  = (const float*)d_in[8];   // [768][3072]
    const float* b_ff1  = (const float*)d_in[9];
    const float* w_ff2  = (const float*)d_in[10];  // [3072][768]
    const float* b_ff2  = (const float*)d_in[11];
    float* out = (float*)d_out;                    // [8192][768] fp32

    // ws layout (uint16 elements), peak 64.5 MB (proven safe)
    uint16_t* ws  = (uint16_t*)d_ws;
    uint16_t* qk  = ws;                            // [8192][1536] Q,K
    uint16_t* ffc = ws;                            // [8192][1536] (reuses dead qk)
    uint16_t* vT  = ws + (size_t)12582912;         // [8][768][1024]
    uint16_t* h   = ws + (size_t)18874368;         // [8192][768]
    uint16_t* WqT = ws + (size_t)25165824;         // [2304][768]
    uint16_t* WoT = ws + (size_t)26935296;         // [768][768]
    uint16_t* W1T = ws + (size_t)27525120;         // [3072][768]
    uint16_t* W2T = ws + (size_t)29884416;         // [768][3072]

    // all four weight transposes in one launch
    hipLaunchKernelGGL(transpose_all, dim3(6912), dim3(32, 8), 0, stream,
                       w_qkv, w_out, w_ff1, w_ff2, WqT, WoT, W1T, W2T);

    // h = LN1(x)
    hipLaunchKernelGGL(ln_naive, dim3(TOK/4), dim3(256), 0, stream, x, ln1_g, ln1_b, h);
    // qk (+vT split) = h @ w_qkv
    hipLaunchKernelGGL((gemm_bt<false, false, false, false, true>), dim3(QKVN/128, TOK/128), dim3(256), 0, stream,
                       h, WqT, qk, nullptr, 0, nullptr, QKVN, DIM, DIM, DIM, QKLD, vT);
    // attention in-place (O -> Q slots of qk)
    hipLaunchKernelGGL(flash_mfma, dim3(SEQ/128, HEADS, BATCH), dim3(512), 0, stream, qk, vT);
    // d_out(fp32) = x + attnO @ w_out + b_out
    hipLaunchKernelGGL((gemm_bt<true, false, true, true, false>), dim3(DIM/128, TOK/128), dim3(256), 0, stream,
                       qk, WoT, out, b_out, 0, x, DIM, INNER, QKLD, DIM, DIM, nullptr);
    // h = LN2(d_out)
    hipLaunchKernelGGL(ln_naive, dim3(TOK/4), dim3(256), 0, stream, out, ln2_g, ln2_b, h);
    // FFN in two hidden chunks of 1536 (ffc reuses dead qk region)
    for (int c = 0; c < 2; c++) {
        hipLaunchKernelGGL((gemm_bt<true, true, false, false, false>), dim3(1536/128, TOK/128), dim3(256), 0, stream,
                           h, W1T + (size_t)c*1536*DIM, ffc, b_ff1, c*1536, nullptr,
                           1536, DIM, DIM, DIM, 1536, nullptr);
        if (c == 0) {
            hipLaunchKernelGGL((gemm_bt<true, false, true, true, false>), dim3(DIM/128, TOK/128), dim3(256), 0, stream,
                               ffc, W2T + (size_t)c*1536, out, b_ff2, 0, out,
                               DIM, 1536, 1536, FFDIM, DIM, nullptr);
        } else {
            hipLaunchKernelGGL((gemm_bt<false, false, true, true, false>), dim3(DIM/128, TOK/128), dim3(256), 0, stream,
                               ffc, W2T + (size_t)c*1536, out, nullptr, 0, out,
                               DIM, 1536, 1536, FFDIM, DIM, nullptr);
        }
    }
}